// Round 15
// baseline (419.280 us; speedup 1.0000x reference)
//
#include <hip/hip_runtime.h>
#include <hip/hip_bf16.h>

#define NB 4
#define NL 2048
#define NH 8
#define NDM 512
#define ND 64
#define KSPLIT 4
#define QB 8

typedef __attribute__((ext_vector_type(8))) short short8b;
typedef __attribute__((ext_vector_type(4))) float f32x4;

// ---------------- W_V -> bf16 transposed [col][k] (once) ----------------
__global__ void wconv(const float* __restrict__ W, unsigned short* __restrict__ WT) {
  const int g = blockIdx.x * 256 + threadIdx.x;   // 262144
  const int k = g >> 9, c = g & 511;
  __hip_bfloat16 hb = __float2bfloat16(W[(size_t)k * 512 + c]);
  WT[(size_t)c * 512 + k] = *reinterpret_cast<unsigned short*>(&hb);
}

// ---------------- V mean via linearity: colmean(input_V) @ W_V ----------------
__global__ void vmean_colmean(const float* __restrict__ inV, float* __restrict__ parts) {
  const int b = blockIdx.x, seg = blockIdx.y, t = threadIdx.x;   // grid (NB, 64)
  const float* p = inV + ((size_t)b * NL + seg * 32) * NDM;
  float s0 = 0.f, s1 = 0.f;
  for (int r = 0; r < 32; ++r) {
    s0 += p[(size_t)r * NDM + t];
    s1 += p[(size_t)r * NDM + 256 + t];
  }
  parts[((size_t)b * 64 + seg) * NDM + t] = s0;
  parts[((size_t)b * 64 + seg) * NDM + 256 + t] = s1;
}
__global__ void vmean_gemm(const float* __restrict__ parts, const float* __restrict__ Wv,
                           float* __restrict__ Vm) {
  __shared__ float cm[512];
  const int b = blockIdx.x, t = threadIdx.x;      // grid (NB, 2)
  float a0 = 0.f, a1 = 0.f;
  for (int g = 0; g < 64; ++g) {
    a0 += parts[((size_t)b * 64 + g) * NDM + t];
    a1 += parts[((size_t)b * 64 + g) * NDM + 256 + t];
  }
  cm[t] = a0 * (1.f / 2048.f);
  cm[t + 256] = a1 * (1.f / 2048.f);
  __syncthreads();
  const int c0 = blockIdx.y * 256 + t;
  float acc = 0.f;
  for (int k = 0; k < 512; ++k) acc += cm[k] * Wv[(size_t)k * NDM + c0];
  Vm[b * 512 + c0] = acc;
}

// ---------------- Q/K projection: 64Mx128N (2 heads), 8x8 frags, W from global ----------------
// 128 threads = 2 waves. A-only LDS (swizzled transposed). W read per-kk from global (L1-hot).
// grid (32, hcg/2, 2): bm, head-pair, mat.
__global__ __launch_bounds__(128, 4) void proj_qk(
    const float* __restrict__ AQ, const float* __restrict__ AK,
    const float* __restrict__ wQm, const float* __restrict__ wKm,
    int gh0, float* __restrict__ Qc, float* __restrict__ Kc) {
  __shared__ float As_[32 * 68];    // transposed A tile [k][r'], r' = r ^ (((k>>2)&3)<<3)
  const int tid = threadIdx.x;
  const int bm = blockIdx.x;        // 0..31 (64-row tiles)
  const int hp = blockIdx.y;        // head-pair within chunk
  const int mat = blockIdx.z;       // 0=Q 1=K
  const int bh = gh0 + hp * 2;      // even
  const int b = bh >> 3, h = bh & 7;
  const float* A = (mat == 0) ? AQ : AK;
  const float* W = (mat == 0) ? wQm : wKm;
  float* D = (mat == 0) ? Qc : Kc;
  const float* Ab = A + (size_t)b * NL * NDM;
  const int colbase = h * 64;
  const int tm = tid >> 4;          // 0..7  (8 rows each)
  const int tn = tid & 15;          // 0..15 (4 cols per head each)
  float acc0[8][4] = {};
  float acc1[8][4] = {};
  for (int k0 = 0; k0 < 512; k0 += 32) {
    // stage A 64x32 transposed, swizzled scatter (~2-way = free)
#pragma unroll
    for (int i = 0; i < 4; ++i) {
      int s = tid + i * 128;
      int r = s >> 3, c4 = (s & 7) * 4;
      float4 v = *reinterpret_cast<const float4*>(Ab + (size_t)(bm * 64 + r) * 512 + k0 + c4);
      float vv[4] = {v.x, v.y, v.z, v.w};
#pragma unroll
      for (int j = 0; j < 4; ++j) {
        int c = c4 + j;
        int rs = r ^ (((c >> 2) & 3) << 3);
        As_[c * 68 + rs] = vv[j];
      }
    }
    __syncthreads();
#pragma unroll
    for (int kk = 0; kk < 32; ++kk) {
      const int sw = ((kk >> 2) & 3) << 3;
      const int mb = (tm * 8) ^ sw;
      float4 a0 = *reinterpret_cast<const float4*>(&As_[kk * 68 + mb]);
      float4 a1 = *reinterpret_cast<const float4*>(&As_[kk * 68 + mb + 4]);
      const float* wrow = W + (size_t)(k0 + kk) * 512 + colbase + tn * 4;
      float4 w0 = *reinterpret_cast<const float4*>(wrow);        // head h
      float4 w1 = *reinterpret_cast<const float4*>(wrow + 64);   // head h+1
      float a[8] = {a0.x, a0.y, a0.z, a0.w, a1.x, a1.y, a1.z, a1.w};
#pragma unroll
      for (int ii = 0; ii < 8; ++ii) {
        acc0[ii][0] += a[ii] * w0.x; acc0[ii][1] += a[ii] * w0.y;
        acc0[ii][2] += a[ii] * w0.z; acc0[ii][3] += a[ii] * w0.w;
        acc1[ii][0] += a[ii] * w1.x; acc1[ii][1] += a[ii] * w1.y;
        acc1[ii][2] += a[ii] * w1.z; acc1[ii][3] += a[ii] * w1.w;
      }
    }
    __syncthreads();
  }
  const int hl0 = hp * 2, hl1 = hp * 2 + 1;
#pragma unroll
  for (int ii = 0; ii < 8; ++ii) {
    int row = bm * 64 + tm * 8 + ii;
    *reinterpret_cast<float4*>(D + ((size_t)hl0 * NL + row) * ND + tn * 4) =
        make_float4(acc0[ii][0], acc0[ii][1], acc0[ii][2], acc0[ii][3]);
    *reinterpret_cast<float4*>(D + ((size_t)hl1 * NL + row) * ND + tn * 4) =
        make_float4(acc1[ii][0], acc1[ii][1], acc1[ii][2], acc1[ii][3]);
  }
}

// ---------------- V projection: bf16 MFMA 16x16x32, no LDS ----------------
__global__ __launch_bounds__(256) void projV_mfma(
    const float* __restrict__ AV, const unsigned short* __restrict__ WT,
    int gh0, float* __restrict__ Vc) {
  const int wv = threadIdx.x >> 6, l = threadIdx.x & 63;
  const int bm = blockIdx.x;          // 0..31 (64-row tiles)
  const int hl = blockIdx.y;
  const int bh = gh0 + hl;
  const int b = bh >> 3, h = bh & 7;
  const float* Ab = AV + (size_t)b * NL * NDM;
  const int row = bm * 64 + wv * 16 + (l & 15);
  const int kg = (l >> 4) * 8;
  f32x4 acc0 = {}, acc1 = {}, acc2 = {}, acc3 = {};
  for (int k0 = 0; k0 < 512; k0 += 32) {
    const float* ap = Ab + (size_t)row * 512 + k0 + kg;
    short8b af;
#pragma unroll
    for (int j = 0; j < 8; ++j) {
      __hip_bfloat16 hb = __float2bfloat16(ap[j]);
      af[j] = *reinterpret_cast<short*>(&hb);
    }
    const unsigned short* wp = WT + (size_t)(h * 64 + (l & 15)) * 512 + k0 + kg;
    short8b b0 = *reinterpret_cast<const short8b*>(wp);
    short8b b1 = *reinterpret_cast<const short8b*>(wp + 16 * 512);
    short8b b2 = *reinterpret_cast<const short8b*>(wp + 32 * 512);
    short8b b3 = *reinterpret_cast<const short8b*>(wp + 48 * 512);
    acc0 = __builtin_amdgcn_mfma_f32_16x16x32_bf16(af, b0, acc0, 0, 0, 0);
    acc1 = __builtin_amdgcn_mfma_f32_16x16x32_bf16(af, b1, acc1, 0, 0, 0);
    acc2 = __builtin_amdgcn_mfma_f32_16x16x32_bf16(af, b2, acc2, 0, 0, 0);
    acc3 = __builtin_amdgcn_mfma_f32_16x16x32_bf16(af, b3, acc3, 0, 0, 0);
  }
  const int rbase = bm * 64 + wv * 16 + (l >> 4) * 4;
  const int col = l & 15;
#pragma unroll
  for (int j = 0; j < 4; ++j) {
    size_t o = ((size_t)hl * NL + rbase + j) * ND + col;
    Vc[o] = acc0[j];
    Vc[o + 16] = acc1[j];
    Vc[o + 32] = acc2[j];
    Vc[o + 48] = acc3[j];
  }
}

// ---------------- sampled scores, lane=k design (UK compile-time) ----------------
template <int UK>
__global__ __launch_bounds__(256) void sample_scores_t(
    const float* __restrict__ Q, const float* __restrict__ K,
    const int* __restrict__ sampP, float* __restrict__ M) {
  __shared__ float KsAll[4][UK * 66];
  __shared__ float QsAll[4][68];
  const int wv = threadIdx.x >> 6, l = threadIdx.x & 63;
  const int gq = blockIdx.x * 4 + wv;
  const int hl = gq >> 11;
  const int q = gq & 2047;
  float* Ks = KsAll[wv];
  float* Qs = QsAll[wv];
  const float* Kb = K + (size_t)hl * NL * ND;
  Qs[l] = Q[(size_t)gq * ND + l];
  const int base = __builtin_amdgcn_readfirstlane(q) * UK;
#pragma unroll
  for (int r = 0; r < UK; ++r) {
    int kk = sampP[base + r] & (NL - 1);    // clamp: can never fault
    Ks[r * 66 + l] = Kb[(size_t)kk * ND + l];
  }
  __syncthreads();
  const int myk = (l < UK) ? l : (UK - 1);
  float acc = 0.f;
#pragma unroll
  for (int j = 0; j < 32; ++j) {
    float2 kv = *reinterpret_cast<const float2*>(&Ks[myk * 66 + 2 * j]);
    float2 qv = *reinterpret_cast<const float2*>(&Qs[2 * j]);
    acc += kv.x * qv.x + kv.y * qv.y;
  }
  float mval = (l < UK) ? acc : -1e30f;
  float sval = (l < UK) ? acc : 0.f;
#pragma unroll
  for (int o = 32; o; o >>= 1) {
    mval = fmaxf(mval, __shfl_xor(mval, o, 64));
    sval += __shfl_xor(sval, o, 64);
  }
  if (l == 0) M[gq] = mval - sval * (1.f / (float)UK);
}

__global__ void sample_scores_gen(const float* __restrict__ Q, const float* __restrict__ K,
                                  const int* __restrict__ sampP, float* __restrict__ M, int uk) {
  const int wave = threadIdx.x >> 6, lane = threadIdx.x & 63;
  const int gq = blockIdx.x * 4 + wave;
  const int hl = gq >> 11;
  const int q = gq & 2047;
  const float qv = Q[(size_t)gq * ND + lane];
  const float* Kbase = K + (size_t)hl * NL * ND;
  float mx = -1e30f, sm = 0.f;
  for (int k = 0; k < uk; ++k) {
    int kidx = sampP[q * uk + k] & (NL - 1);
    float p = qv * Kbase[(size_t)kidx * ND + lane];
#pragma unroll
    for (int o = 32; o; o >>= 1) p += __shfl_xor(p, o, 64);
    mx = fmaxf(mx, p);
    sm += p;
  }
  if (lane == 0) M[gq] = mx - sm / (float)uk;
}

// ---------------- top-u_q per local head ----------------
__global__ void topk_kernel(const float* __restrict__ M, int* __restrict__ idxo,
                            float* __restrict__ outIdx, int uq) {
  __shared__ float mv[2048];
  __shared__ float bwv[4];
  __shared__ int bwi[4];
  const int bh = blockIdx.x, t = threadIdx.x;
  for (int i = 0; i < 8; ++i) mv[t + i * 256] = M[(size_t)bh * 2048 + t + i * 256];
  __syncthreads();
  for (int it = 0; it < uq; ++it) {
    float best = -1e38f; int bidx = 1 << 30;
#pragma unroll
    for (int i = 0; i < 8; ++i) {
      int id = t + i * 256;
      float v = mv[id];
      if (v > best || (v == best && id < bidx)) { best = v; bidx = id; }
    }
#pragma unroll
    for (int o = 32; o; o >>= 1) {
      float ov = __shfl_xor(best, o, 64);
      int oi = __shfl_xor(bidx, o, 64);
      if (ov > best || (ov == best && oi < bidx)) { best = ov; bidx = oi; }
    }
    if ((t & 63) == 0) { bwv[t >> 6] = best; bwi[t >> 6] = bidx; }
    __syncthreads();
    if (t == 0) {
      float bb = bwv[0]; int bi2 = bwi[0];
#pragma unroll
      for (int w = 1; w < 4; ++w) {
        if (bwv[w] > bb || (bwv[w] == bb && bwi[w] < bi2)) { bb = bwv[w]; bi2 = bwi[w]; }
      }
      int sel = bi2 & (NL - 1);
      idxo[bh * uq + it] = sel;
      outIdx[bh * uq + it] = (float)sel;
      mv[sel] = -1e38f;
    }
    __syncthreads();
  }
}

// ---------------- flash attention partials ----------------
__global__ __launch_bounds__(256) void attn_part(
    const float* __restrict__ Qw, const float* __restrict__ Kw, const float* __restrict__ Vw,
    const int* __restrict__ idxo, float* __restrict__ pacc, float* __restrict__ pml, int uq) {
  __shared__ float Qs[QB][68];
  __shared__ float Ks[64][68];
  __shared__ float Vs[64][68];
  __shared__ float sc[QB][66];
  __shared__ float accs[QB][68];
  const int hl = blockIdx.x, qg = blockIdx.y, ks = blockIdx.z;
  const int t = threadIdx.x;
#pragma unroll
  for (int i = 0; i < 2; ++i) {
    int s = t + i * 256;
    int q = s >> 6, d = s & 63;
    int u = qg * QB + q;
    float v = 0.f;
    if (u < uq) {
      int qi = idxo[hl * uq + u] & (NL - 1);
      v = Qw[((size_t)hl * NL + qi) * ND + d];
    }
    Qs[q][d] = v;
    accs[q][d] = 0.f;
  }
  float m_run = -1e30f, l_run = 0.f;
  const int q2 = t >> 5, ln = t & 31;
  __syncthreads();
  const int kbeg = ks * (NL / KSPLIT);
  for (int k0 = kbeg; k0 < kbeg + NL / KSPLIT; k0 += 64) {
#pragma unroll
    for (int i = 0; i < 4; ++i) {
      int s = t + i * 256;
      int r = s >> 4, c4 = (s & 15) * 4;
      *reinterpret_cast<float4*>(&Ks[r][c4]) =
          *reinterpret_cast<const float4*>(Kw + ((size_t)hl * NL + k0 + r) * ND + c4);
      *reinterpret_cast<float4*>(&Vs[r][c4]) =
          *reinterpret_cast<const float4*>(Vw + ((size_t)hl * NL + k0 + r) * ND + c4);
    }
    __syncthreads();
    {
      const int q = t & 7, kk = t >> 3;
      float d0 = 0.f, d1 = 0.f;
#pragma unroll
      for (int dd = 0; dd < 64; dd += 4) {
        float4 qv = *reinterpret_cast<const float4*>(&Qs[q][dd]);
        float4 ka = *reinterpret_cast<const float4*>(&Ks[kk][dd]);
        float4 kb = *reinterpret_cast<const float4*>(&Ks[kk + 32][dd]);
        d0 += qv.x * ka.x + qv.y * ka.y + qv.z * ka.z + qv.w * ka.w;
        d1 += qv.x * kb.x + qv.y * kb.y + qv.z * kb.z + qv.w * kb.w;
      }
      sc[q][kk] = d0 * 0.125f;
      sc[q][kk + 32] = d1 * 0.125f;
    }
    __syncthreads();
    {
      float s0 = sc[q2][ln], s1 = sc[q2][ln + 32];
      float tmax = fmaxf(s0, s1);
#pragma unroll
      for (int o = 16; o; o >>= 1) tmax = fmaxf(tmax, __shfl_xor(tmax, o, 64));
      float mnew = fmaxf(m_run, tmax);
      float scl = __expf(m_run - mnew);
      float p0 = __expf(s0 - mnew), p1 = __expf(s1 - mnew);
      float tsum = p0 + p1;
#pragma unroll
      for (int o = 16; o; o >>= 1) tsum += __shfl_xor(tsum, o, 64);
      l_run = l_run * scl + tsum;
      m_run = mnew;
      sc[q2][ln] = p0; sc[q2][ln + 32] = p1;
      float a0 = accs[q2][2 * ln] * scl, a1 = accs[q2][2 * ln + 1] * scl;
#pragma unroll 8
      for (int k = 0; k < 64; ++k) {
        float p = sc[q2][k];
        a0 += p * Vs[k][2 * ln];
        a1 += p * Vs[k][2 * ln + 1];
      }
      accs[q2][2 * ln] = a0; accs[q2][2 * ln + 1] = a1;
    }
    __syncthreads();
  }
  const int u = qg * QB + q2;
  if (u < uq) {
    size_t g = ((size_t)hl * uq + u) * KSPLIT + ks;
    pacc[g * ND + 2 * ln] = accs[q2][2 * ln];
    pacc[g * ND + 2 * ln + 1] = accs[q2][2 * ln + 1];
    if (ln == 0) { pml[g * 2] = m_run; pml[g * 2 + 1] = l_run; }
  }
}

// ---------------- merge split-K partials ----------------
__global__ void attn_merge(const float* __restrict__ pacc, const float* __restrict__ pml,
                           float* __restrict__ vals, int uq) {
  const int g = blockIdx.x;
  const int d = threadIdx.x;
  float mstar = -1e30f;
#pragma unroll
  for (int s = 0; s < KSPLIT; ++s) mstar = fmaxf(mstar, pml[((size_t)g * KSPLIT + s) * 2]);
  float num = 0.f, den = 0.f;
#pragma unroll
  for (int s = 0; s < KSPLIT; ++s) {
    float e = __expf(pml[((size_t)g * KSPLIT + s) * 2] - mstar);
    den += e * pml[((size_t)g * KSPLIT + s) * 2 + 1];
    num += e * pacc[((size_t)g * KSPLIT + s) * ND + d];
  }
  vals[(size_t)g * ND + d] = num / den;
}

// ---------------- selmap ----------------
__global__ void selmap_init(short* __restrict__ selmap) {
  const int g = blockIdx.x * 256 + threadIdx.x;
  selmap[g] = -1;
  selmap[g + 32768] = -1;
}
__global__ void selmap_fill(const int* __restrict__ idxo, short* __restrict__ selmap, int uq) {
  const int g = blockIdx.x * 256 + threadIdx.x;
  if (g >= NB * NH * uq) return;
  const int bh = g / uq, u = g - bh * uq;
  const int b = bh >> 3, h = bh & 7;
  const int l = idxo[g] & (NL - 1);
  selmap[((size_t)b * NL + l) * NH + h] = (short)u;
}

// ---------------- base[b,:] = concat_h(Vm) @ W_fc ----------------
__global__ void base_gemm(const float* __restrict__ Vm, const float* __restrict__ Wfc,
                          float* __restrict__ base) {
  __shared__ float vm[512];
  const int b = blockIdx.x, t = threadIdx.x;
  vm[t] = Vm[b * 512 + t];
  vm[t + 256] = Vm[b * 512 + t + 256];
  __syncthreads();
  const int c0 = blockIdx.y * 256 + t;
  float acc = 0.f;
  for (int k = 0; k < 512; ++k) acc += vm[k] * Wfc[(size_t)k * 512 + c0];
  base[b * 512 + c0] = acc;
}

// ---------------- corr = (vals - Vm) @ W_fc_head ----------------
__global__ void corr_gemm(const float* __restrict__ vals, const float* __restrict__ Vm,
                          const float* __restrict__ Wfc, float* __restrict__ corr, int uq) {
  __shared__ float diff[64];
  const int g = blockIdx.x, t = threadIdx.x;
  const int bh = g / uq;
  const int h = bh & 7;
  if (t < 64) diff[t] = vals[(size_t)g * 64 + t] - Vm[bh * 64 + t];
  __syncthreads();
  float a0 = 0.f, a1 = 0.f;
#pragma unroll
  for (int d = 0; d < 64; ++d) {
    a0 += diff[d] * Wfc[(size_t)(h * 64 + d) * 512 + t];
    a1 += diff[d] * Wfc[(size_t)(h * 64 + d) * 512 + t + 256];
  }
  corr[(size_t)g * 512 + t] = a0;
  corr[(size_t)g * 512 + t + 256] = a1;
}

// ---------------- fused residual + corrections + LayerNorm ----------------
__global__ void ln_fused(const float* __restrict__ base, const float* __restrict__ resid,
                         const float* __restrict__ corr, const short* __restrict__ selmap,
                         const float* __restrict__ gamma, const float* __restrict__ beta,
                         float* __restrict__ out, int uq) {
  __shared__ float red[256];
  const int row = blockIdx.x, t = threadIdx.x;
  const int b = row >> 11;
  float y0 = base[b * 512 + t] + resid[(size_t)row * 512 + t];
  float y1 = base[b * 512 + 256 + t] + resid[(size_t)row * 512 + 256 + t];
#pragma unroll
  for (int h = 0; h < NH; ++h) {
    int s = selmap[(size_t)row * NH + h];
    if (s >= 0 && s < uq) {
      const float* cp = corr + (size_t)((b * NH + h) * uq + s) * 512;
      y0 += cp[t];
      y1 += cp[t + 256];
    }
  }
  red[t] = y0 + y1;
  __syncthreads();
  for (int s = 128; s; s >>= 1) { if (t < s) red[t] += red[t + s]; __syncthreads(); }
  const float mu = red[0] * (1.f / 512.f);
  __syncthreads();
  const float d0 = y0 - mu, d1 = y1 - mu;
  red[t] = d0 * d0 + d1 * d1;
  __syncthreads();
  for (int s = 128; s; s >>= 1) { if (t < s) red[t] += red[t + s]; __syncthreads(); }
  const float rs = rsqrtf(red[0] * (1.f / 512.f) + 1e-5f);
  __syncthreads();
  out[(size_t)row * 512 + t] = d0 * rs * gamma[t] + beta[t];
  out[(size_t)row * 512 + 256 + t] = d1 * rs * gamma[256 + t] + beta[256 + t];
}

extern "C" void kernel_launch(void* const* d_in, const int* in_sizes, int n_in,
                              void* d_out, int out_size, void* d_ws, size_t ws_size,
                              hipStream_t stream) {
  const float* inQ = (const float*)d_in[0];
  const float* inK = (const float*)d_in[1];
  const float* inV = (const float*)d_in[2];
  const float* wQ = (const float*)d_in[3];
  const float* wK = (const float*)d_in[4];
  const float* wV = (const float*)d_in[5];
  const float* wFC = (const float*)d_in[6];
  const float* gamma = (const float*)d_in[7];
  const float* beta = (const float*)d_in[8];
  const int* samp = (const int*)d_in[9];

  const int nsamp = in_sizes[9];   // 77824
  const int uk = nsamp / NL;       // 38
  const int uq = uk;
  const int nqg = (uq + QB - 1) / QB;

  if (out_size < NB * NL * NDM + NB * NH * uq) return;

  const size_t perH = 3 * 131072 + 2048 + (size_t)uq * KSPLIT * 64 + (size_t)uq * KSPLIT * 2;
  const size_t fixed = (size_t)32 * uq * 64 + 2048 + 2048 + (size_t)32 * uq * 512
                     + (size_t)32 * uq + 32768 + 131072 + 131072 + 256;
  int hcg = 0;
  for (int c = 32; c >= 2; c >>= 1) {   // even (proj_qk handles head pairs)
    if ((perH * (size_t)c + fixed + 256) * 4ull <= ws_size) { hcg = c; break; }
  }
  if (hcg == 0) return;

  float* ws = (float*)d_ws;
  float* Qc = ws;
  float* Kc = Qc + (size_t)hcg * 131072;
  float* Vc = Kc + (size_t)hcg * 131072;
  float* Mb = Vc + (size_t)hcg * 131072;
  float* pacc = Mb + (size_t)hcg * 2048;
  float* pml = pacc + (size_t)hcg * uq * KSPLIT * 64;
  float* vals = pml + (size_t)hcg * uq * KSPLIT * 2;
  float* Vm = vals + (size_t)32 * uq * 64;
  float* base = Vm + 2048;
  float* corr = base + 2048;
  int* idxo = (int*)(corr + (size_t)32 * uq * 512);
  short* selmap = (short*)(idxo + (size_t)32 * uq);
  unsigned short* WTv = (unsigned short*)(selmap + 65536);   // 262144 bf16
  float* vparts = (float*)(WTv + 262144);                    // 131072 f

  float* out = (float*)d_out;
  float* outIdx = out + (size_t)NB * NL * NDM;

  wconv<<<1024, 256, 0, stream>>>(wV, WTv);
  vmean_colmean<<<dim3(NB, 64), 256, 0, stream>>>(inV, vparts);
  vmean_gemm<<<dim3(NB, 2), 256, 0, stream>>>(vparts, wV, Vm);

  for (int gh0 = 0; gh0 < NB * NH; gh0 += hcg) {
    proj_qk<<<dim3(32, hcg / 2, 2), 128, 0, stream>>>(inQ, inK, wQ, wK, gh0, Qc, Kc);
    projV_mfma<<<dim3(32, hcg), 256, 0, stream>>>(inV, WTv, gh0, Vc);
    if (uk == 38)
      sample_scores_t<38><<<hcg * NL / 4, 256, 0, stream>>>(Qc, Kc, samp, Mb);
    else
      sample_scores_gen<<<hcg * NL / 4, 256, 0, stream>>>(Qc, Kc, samp, Mb, uk);
    topk_kernel<<<hcg, 256, 0, stream>>>(Mb, idxo + (size_t)gh0 * uq,
                                         outIdx + (size_t)gh0 * uq, uq);
    attn_part<<<dim3(hcg, nqg, KSPLIT), 256, 0, stream>>>(Qc, Kc, Vc,
                                                          idxo + (size_t)gh0 * uq,
                                                          pacc, pml, uq);
    attn_merge<<<hcg * uq, 64, 0, stream>>>(pacc, pml, vals + (size_t)gh0 * uq * ND, uq);
  }

  selmap_init<<<NB * NL * NH / 2 / 256, 256, 0, stream>>>(selmap);
  selmap_fill<<<(NB * NH * uq + 255) / 256, 256, 0, stream>>>(idxo, selmap, uq);
  base_gemm<<<dim3(NB, 2), 256, 0, stream>>>(Vm, wFC, base);
  corr_gemm<<<NB * NH * uq, 256, 0, stream>>>(vals, Vm, wFC, corr, uq);
  ln_fused<<<NB * NL, 256, 0, stream>>>(base, inQ, corr, selmap, gamma, beta, out, uq);
}

// Round 16
// 361.443 us; speedup vs baseline: 1.1600x; 1.1600x over previous
//
#include <hip/hip_runtime.h>
#include <hip/hip_bf16.h>

#define NB 4
#define NL 2048
#define NH 8
#define NDM 512
#define ND 64
#define KSPLIT 8
#define QB 8

typedef __attribute__((ext_vector_type(8))) short short8b;
typedef __attribute__((ext_vector_type(4))) float f32x4;

// ---------------- W_V -> bf16 transposed [col][k] (once) ----------------
__global__ void wconv(const float* __restrict__ W, unsigned short* __restrict__ WT) {
  const int g = blockIdx.x * 256 + threadIdx.x;   // 262144
  const int k = g >> 9, c = g & 511;
  __hip_bfloat16 hb = __float2bfloat16(W[(size_t)k * 512 + c]);
  WT[(size_t)c * 512 + k] = *reinterpret_cast<unsigned short*>(&hb);
}

// ---------------- V mean via linearity: colmean(input_V) @ W_V ----------------
__global__ void vmean_colmean(const float* __restrict__ inV, float* __restrict__ parts) {
  const int b = blockIdx.x, seg = blockIdx.y, t = threadIdx.x;   // grid (NB, 64)
  const float* p = inV + ((size_t)b * NL + seg * 32) * NDM;
  float s0 = 0.f, s1 = 0.f;
  for (int r = 0; r < 32; ++r) {
    s0 += p[(size_t)r * NDM + t];
    s1 += p[(size_t)r * NDM + 256 + t];
  }
  parts[((size_t)b * 64 + seg) * NDM + t] = s0;
  parts[((size_t)b * 64 + seg) * NDM + 256 + t] = s1;
}
__global__ void vmean_gemm(const float* __restrict__ parts, const float* __restrict__ Wv,
                           float* __restrict__ Vm) {
  __shared__ float cm[512];
  const int b = blockIdx.x, t = threadIdx.x;      // grid (NB, 2)
  float a0 = 0.f, a1 = 0.f;
  for (int g = 0; g < 64; ++g) {
    a0 += parts[((size_t)b * 64 + g) * NDM + t];
    a1 += parts[((size_t)b * 64 + g) * NDM + 256 + t];
  }
  cm[t] = a0 * (1.f / 2048.f);
  cm[t + 256] = a1 * (1.f / 2048.f);
  __syncthreads();
  const int c0 = blockIdx.y * 256 + t;
  float acc = 0.f;
  for (int k = 0; k < 512; ++k) acc += cm[k] * Wv[(size_t)k * NDM + c0];
  Vm[b * 512 + c0] = acc;
}

// ---------------- Q/K projection (fp32, r12-proven structure, z = 0:Q 1:K) ----------------
__global__ __launch_bounds__(256, 4) void proj3(
    const float* __restrict__ AQ, const float* __restrict__ AK,
    const float* __restrict__ wQm, const float* __restrict__ wKm,
    int gh0, float* __restrict__ Qc, float* __restrict__ Kc) {
  __shared__ float As_[32 * 132];   // transposed A tile: As[kk][m]
  __shared__ float Ws_[32 * 68];    // W tile: Ws[kk][n]
  const int tid = threadIdx.x;
  const int bm = blockIdx.x;
  const int hl = blockIdx.y;
  const int mat = blockIdx.z;       // 0=Q 1=K
  const int bh = gh0 + hl;
  const int b = bh >> 3, h = bh & 7;
  const float* A = (mat == 0) ? AQ : AK;
  const float* W = (mat == 0) ? wQm : wKm;
  float* D = (mat == 0) ? Qc : Kc;
  const float* Ab = A + (size_t)b * NL * NDM;
  const int colbase = h * 64;
  const int tm = tid >> 4, tn = tid & 15;
  float acc[8][4] = {};
  for (int k0 = 0; k0 < 512; k0 += 32) {
#pragma unroll
    for (int i = 0; i < 4; ++i) {
      int s = tid + i * 256;
      int r = s >> 3, c4 = (s & 7) * 4;
      float4 v = *reinterpret_cast<const float4*>(Ab + (size_t)(bm * 128 + r) * 512 + k0 + c4);
      As_[(c4 + 0) * 132 + r] = v.x;
      As_[(c4 + 1) * 132 + r] = v.y;
      As_[(c4 + 2) * 132 + r] = v.z;
      As_[(c4 + 3) * 132 + r] = v.w;
    }
#pragma unroll
    for (int i = 0; i < 2; ++i) {
      int s = tid + i * 256;
      int r = s >> 4, c4 = (s & 15) * 4;
      *reinterpret_cast<float4*>(&Ws_[r * 68 + c4]) =
          *reinterpret_cast<const float4*>(W + (size_t)(k0 + r) * 512 + colbase + c4);
    }
    __syncthreads();
#pragma unroll
    for (int kk = 0; kk < 32; ++kk) {
      float4 a0 = *reinterpret_cast<const float4*>(&As_[kk * 132 + tm * 4]);
      float4 a1 = *reinterpret_cast<const float4*>(&As_[kk * 132 + 64 + tm * 4]);
      float4 w  = *reinterpret_cast<const float4*>(&Ws_[kk * 68 + tn * 4]);
      float a[8] = {a0.x, a0.y, a0.z, a0.w, a1.x, a1.y, a1.z, a1.w};
      float wv[4] = {w.x, w.y, w.z, w.w};
#pragma unroll
      for (int ii = 0; ii < 8; ++ii)
#pragma unroll
        for (int jj = 0; jj < 4; ++jj) acc[ii][jj] += a[ii] * wv[jj];
    }
    __syncthreads();
  }
#pragma unroll
  for (int ii = 0; ii < 8; ++ii) {
    int row = bm * 128 + ((ii < 4) ? (tm * 4 + ii) : (64 + tm * 4 + (ii - 4)));
    float4 v = make_float4(acc[ii][0], acc[ii][1], acc[ii][2], acc[ii][3]);
    *reinterpret_cast<float4*>(D + ((size_t)hl * NL + row) * ND + tn * 4) = v;
  }
}

// ---------------- V projection: bf16 MFMA 16x16x32, no LDS ----------------
__global__ __launch_bounds__(256) void projV_mfma(
    const float* __restrict__ AV, const unsigned short* __restrict__ WT,
    int gh0, float* __restrict__ Vc) {
  const int wv = threadIdx.x >> 6, l = threadIdx.x & 63;
  const int bm = blockIdx.x;          // 0..31 (64-row tiles)
  const int hl = blockIdx.y;
  const int bh = gh0 + hl;
  const int b = bh >> 3, h = bh & 7;
  const float* Ab = AV + (size_t)b * NL * NDM;
  const int row = bm * 64 + wv * 16 + (l & 15);
  const int kg = (l >> 4) * 8;
  f32x4 acc0 = {}, acc1 = {}, acc2 = {}, acc3 = {};
  for (int k0 = 0; k0 < 512; k0 += 32) {
    const float* ap = Ab + (size_t)row * 512 + k0 + kg;
    short8b af;
#pragma unroll
    for (int j = 0; j < 8; ++j) {
      __hip_bfloat16 hb = __float2bfloat16(ap[j]);
      af[j] = *reinterpret_cast<short*>(&hb);
    }
    const unsigned short* wp = WT + (size_t)(h * 64 + (l & 15)) * 512 + k0 + kg;
    short8b b0 = *reinterpret_cast<const short8b*>(wp);
    short8b b1 = *reinterpret_cast<const short8b*>(wp + 16 * 512);
    short8b b2 = *reinterpret_cast<const short8b*>(wp + 32 * 512);
    short8b b3 = *reinterpret_cast<const short8b*>(wp + 48 * 512);
    acc0 = __builtin_amdgcn_mfma_f32_16x16x32_bf16(af, b0, acc0, 0, 0, 0);
    acc1 = __builtin_amdgcn_mfma_f32_16x16x32_bf16(af, b1, acc1, 0, 0, 0);
    acc2 = __builtin_amdgcn_mfma_f32_16x16x32_bf16(af, b2, acc2, 0, 0, 0);
    acc3 = __builtin_amdgcn_mfma_f32_16x16x32_bf16(af, b3, acc3, 0, 0, 0);
  }
  const int rbase = bm * 64 + wv * 16 + (l >> 4) * 4;
  const int col = l & 15;
#pragma unroll
  for (int j = 0; j < 4; ++j) {
    size_t o = ((size_t)hl * NL + rbase + j) * ND + col;
    Vc[o] = acc0[j];
    Vc[o + 16] = acc1[j];
    Vc[o + 32] = acc2[j];
    Vc[o + 48] = acc3[j];
  }
}

// ---------------- sampled scores, lane=k design (UK compile-time) ----------------
template <int UK>
__global__ __launch_bounds__(256) void sample_scores_t(
    const float* __restrict__ Q, const float* __restrict__ K,
    const int* __restrict__ sampP, float* __restrict__ M) {
  __shared__ float KsAll[4][UK * 66];
  __shared__ float QsAll[4][68];
  const int wv = threadIdx.x >> 6, l = threadIdx.x & 63;
  const int gq = blockIdx.x * 4 + wv;
  const int hl = gq >> 11;
  const int q = gq & 2047;
  float* Ks = KsAll[wv];
  float* Qs = QsAll[wv];
  const float* Kb = K + (size_t)hl * NL * ND;
  Qs[l] = Q[(size_t)gq * ND + l];
  const int base = __builtin_amdgcn_readfirstlane(q) * UK;
#pragma unroll
  for (int r = 0; r < UK; ++r) {
    int kk = sampP[base + r] & (NL - 1);    // clamp: can never fault
    Ks[r * 66 + l] = Kb[(size_t)kk * ND + l];
  }
  __syncthreads();
  const int myk = (l < UK) ? l : (UK - 1);
  float acc = 0.f;
#pragma unroll
  for (int j = 0; j < 32; ++j) {
    float2 kv = *reinterpret_cast<const float2*>(&Ks[myk * 66 + 2 * j]);
    float2 qv = *reinterpret_cast<const float2*>(&Qs[2 * j]);
    acc += kv.x * qv.x + kv.y * qv.y;
  }
  float mval = (l < UK) ? acc : -1e30f;
  float sval = (l < UK) ? acc : 0.f;
#pragma unroll
  for (int o = 32; o; o >>= 1) {
    mval = fmaxf(mval, __shfl_xor(mval, o, 64));
    sval += __shfl_xor(sval, o, 64);
  }
  if (l == 0) M[gq] = mval - sval * (1.f / (float)UK);
}

__global__ void sample_scores_gen(const float* __restrict__ Q, const float* __restrict__ K,
                                  const int* __restrict__ sampP, float* __restrict__ M, int uk) {
  const int wave = threadIdx.x >> 6, lane = threadIdx.x & 63;
  const int gq = blockIdx.x * 4 + wave;
  const int hl = gq >> 11;
  const int q = gq & 2047;
  const float qv = Q[(size_t)gq * ND + lane];
  const float* Kbase = K + (size_t)hl * NL * ND;
  float mx = -1e30f, sm = 0.f;
  for (int k = 0; k < uk; ++k) {
    int kidx = sampP[q * uk + k] & (NL - 1);
    float p = qv * Kbase[(size_t)kidx * ND + lane];
#pragma unroll
    for (int o = 32; o; o >>= 1) p += __shfl_xor(p, o, 64);
    mx = fmaxf(mx, p);
    sm += p;
  }
  if (lane == 0) M[gq] = mx - sm / (float)uk;
}

// ---------------- top-u_q per local head ----------------
__global__ void topk_kernel(const float* __restrict__ M, int* __restrict__ idxo,
                            float* __restrict__ outIdx, int uq) {
  __shared__ float mv[2048];
  __shared__ float bwv[4];
  __shared__ int bwi[4];
  const int bh = blockIdx.x, t = threadIdx.x;
  for (int i = 0; i < 8; ++i) mv[t + i * 256] = M[(size_t)bh * 2048 + t + i * 256];
  __syncthreads();
  for (int it = 0; it < uq; ++it) {
    float best = -1e38f; int bidx = 1 << 30;
#pragma unroll
    for (int i = 0; i < 8; ++i) {
      int id = t + i * 256;
      float v = mv[id];
      if (v > best || (v == best && id < bidx)) { best = v; bidx = id; }
    }
#pragma unroll
    for (int o = 32; o; o >>= 1) {
      float ov = __shfl_xor(best, o, 64);
      int oi = __shfl_xor(bidx, o, 64);
      if (ov > best || (ov == best && oi < bidx)) { best = ov; bidx = oi; }
    }
    if ((t & 63) == 0) { bwv[t >> 6] = best; bwi[t >> 6] = bidx; }
    __syncthreads();
    if (t == 0) {
      float bb = bwv[0]; int bi2 = bwi[0];
#pragma unroll
      for (int w = 1; w < 4; ++w) {
        if (bwv[w] > bb || (bwv[w] == bb && bwi[w] < bi2)) { bb = bwv[w]; bi2 = bwi[w]; }
      }
      int sel = bi2 & (NL - 1);
      idxo[bh * uq + it] = sel;
      outIdx[bh * uq + it] = (float)sel;
      mv[sel] = -1e38f;
    }
    __syncthreads();
  }
}

// ---------------- flash attention partials: grid (hcg, nqg, KSPLIT) ----------------
__global__ __launch_bounds__(256) void attn_part(
    const float* __restrict__ Qw, const float* __restrict__ Kw, const float* __restrict__ Vw,
    const int* __restrict__ idxo, float* __restrict__ pacc, float* __restrict__ pml, int uq) {
  __shared__ float Qs[QB][68];
  __shared__ float Ks[64][68];
  __shared__ float Vs[64][68];
  __shared__ float sc[QB][66];
  __shared__ float accs[QB][68];
  const int hl = blockIdx.x, qg = blockIdx.y, ks = blockIdx.z;
  const int t = threadIdx.x;
#pragma unroll
  for (int i = 0; i < 2; ++i) {
    int s = t + i * 256;
    int q = s >> 6, d = s & 63;
    int u = qg * QB + q;
    float v = 0.f;
    if (u < uq) {
      int qi = idxo[hl * uq + u] & (NL - 1);
      v = Qw[((size_t)hl * NL + qi) * ND + d];
    }
    Qs[q][d] = v;
    accs[q][d] = 0.f;
  }
  float m_run = -1e30f, l_run = 0.f;
  const int q2 = t >> 5, ln = t & 31;
  __syncthreads();
  const int kbeg = ks * (NL / KSPLIT);
  for (int k0 = kbeg; k0 < kbeg + NL / KSPLIT; k0 += 64) {
#pragma unroll
    for (int i = 0; i < 4; ++i) {
      int s = t + i * 256;
      int r = s >> 4, c4 = (s & 15) * 4;
      *reinterpret_cast<float4*>(&Ks[r][c4]) =
          *reinterpret_cast<const float4*>(Kw + ((size_t)hl * NL + k0 + r) * ND + c4);
      *reinterpret_cast<float4*>(&Vs[r][c4]) =
          *reinterpret_cast<const float4*>(Vw + ((size_t)hl * NL + k0 + r) * ND + c4);
    }
    __syncthreads();
    {
      const int q = t & 7, kk = t >> 3;
      float d0 = 0.f, d1 = 0.f;
#pragma unroll
      for (int dd = 0; dd < 64; dd += 4) {
        float4 qv = *reinterpret_cast<const float4*>(&Qs[q][dd]);
        float4 ka = *reinterpret_cast<const float4*>(&Ks[kk][dd]);
        float4 kb = *reinterpret_cast<const float4*>(&Ks[kk + 32][dd]);
        d0 += qv.x * ka.x + qv.y * ka.y + qv.z * ka.z + qv.w * ka.w;
        d1 += qv.x * kb.x + qv.y * kb.y + qv.z * kb.z + qv.w * kb.w;
      }
      sc[q][kk] = d0 * 0.125f;
      sc[q][kk + 32] = d1 * 0.125f;
    }
    __syncthreads();
    {
      float s0 = sc[q2][ln], s1 = sc[q2][ln + 32];
      float tmax = fmaxf(s0, s1);
#pragma unroll
      for (int o = 16; o; o >>= 1) tmax = fmaxf(tmax, __shfl_xor(tmax, o, 64));
      float mnew = fmaxf(m_run, tmax);
      float scl = __expf(m_run - mnew);
      float p0 = __expf(s0 - mnew), p1 = __expf(s1 - mnew);
      float tsum = p0 + p1;
#pragma unroll
      for (int o = 16; o; o >>= 1) tsum += __shfl_xor(tsum, o, 64);
      l_run = l_run * scl + tsum;
      m_run = mnew;
      sc[q2][ln] = p0; sc[q2][ln + 32] = p1;
      float a0 = accs[q2][2 * ln] * scl, a1 = accs[q2][2 * ln + 1] * scl;
#pragma unroll 8
      for (int k = 0; k < 64; ++k) {
        float p = sc[q2][k];
        a0 += p * Vs[k][2 * ln];
        a1 += p * Vs[k][2 * ln + 1];
      }
      accs[q2][2 * ln] = a0; accs[q2][2 * ln + 1] = a1;
    }
    __syncthreads();
  }
  const int u = qg * QB + q2;
  if (u < uq) {
    size_t g = ((size_t)hl * uq + u) * KSPLIT + ks;
    pacc[g * ND + 2 * ln] = accs[q2][2 * ln];
    pacc[g * ND + 2 * ln + 1] = accs[q2][2 * ln + 1];
    if (ln == 0) { pml[g * 2] = m_run; pml[g * 2 + 1] = l_run; }
  }
}

// ---------------- merge split-K partials ----------------
__global__ void attn_merge(const float* __restrict__ pacc, const float* __restrict__ pml,
                           float* __restrict__ vals, int uq) {
  const int g = blockIdx.x;
  const int d = threadIdx.x;
  float mstar = -1e30f;
#pragma unroll
  for (int s = 0; s < KSPLIT; ++s) mstar = fmaxf(mstar, pml[((size_t)g * KSPLIT + s) * 2]);
  float num = 0.f, den = 0.f;
#pragma unroll
  for (int s = 0; s < KSPLIT; ++s) {
    float e = __expf(pml[((size_t)g * KSPLIT + s) * 2] - mstar);
    den += e * pml[((size_t)g * KSPLIT + s) * 2 + 1];
    num += e * pacc[((size_t)g * KSPLIT + s) * ND + d];
  }
  vals[(size_t)g * ND + d] = num / den;
}

// ---------------- selmap ----------------
__global__ void selmap_init(short* __restrict__ selmap) {
  const int g = blockIdx.x * 256 + threadIdx.x;
  selmap[g] = -1;
  selmap[g + 32768] = -1;
}
__global__ void selmap_fill(const int* __restrict__ idxo, short* __restrict__ selmap, int uq) {
  const int g = blockIdx.x * 256 + threadIdx.x;
  if (g >= NB * NH * uq) return;
  const int bh = g / uq, u = g - bh * uq;
  const int b = bh >> 3, h = bh & 7;
  const int l = idxo[g] & (NL - 1);
  selmap[((size_t)b * NL + l) * NH + h] = (short)u;
}

// ---------------- base[b,:] = concat_h(Vm) @ W_fc ----------------
__global__ void base_gemm(const float* __restrict__ Vm, const float* __restrict__ Wfc,
                          float* __restrict__ base) {
  __shared__ float vm[512];
  const int b = blockIdx.x, t = threadIdx.x;
  vm[t] = Vm[b * 512 + t];
  vm[t + 256] = Vm[b * 512 + t + 256];
  __syncthreads();
  const int c0 = blockIdx.y * 256 + t;
  float acc = 0.f;
  for (int k = 0; k < 512; ++k) acc += vm[k] * Wfc[(size_t)k * 512 + c0];
  base[b * 512 + c0] = acc;
}

// ---------------- corr = (vals - Vm) @ W_fc_head ----------------
__global__ void corr_gemm(const float* __restrict__ vals, const float* __restrict__ Vm,
                          const float* __restrict__ Wfc, float* __restrict__ corr, int uq) {
  __shared__ float diff[64];
  const int g = blockIdx.x, t = threadIdx.x;
  const int bh = g / uq;
  const int h = bh & 7;
  if (t < 64) diff[t] = vals[(size_t)g * 64 + t] - Vm[bh * 64 + t];
  __syncthreads();
  float a0 = 0.f, a1 = 0.f;
#pragma unroll
  for (int d = 0; d < 64; ++d) {
    a0 += diff[d] * Wfc[(size_t)(h * 64 + d) * 512 + t];
    a1 += diff[d] * Wfc[(size_t)(h * 64 + d) * 512 + t + 256];
  }
  corr[(size_t)g * 512 + t] = a0;
  corr[(size_t)g * 512 + t + 256] = a1;
}

// ---------------- fused residual + corrections + LayerNorm ----------------
__global__ void ln_fused(const float* __restrict__ base, const float* __restrict__ resid,
                         const float* __restrict__ corr, const short* __restrict__ selmap,
                         const float* __restrict__ gamma, const float* __restrict__ beta,
                         float* __restrict__ out, int uq) {
  __shared__ float red[256];
  const int row = blockIdx.x, t = threadIdx.x;
  const int b = row >> 11;
  float y0 = base[b * 512 + t] + resid[(size_t)row * 512 + t];
  float y1 = base[b * 512 + 256 + t] + resid[(size_t)row * 512 + 256 + t];
#pragma unroll
  for (int h = 0; h < NH; ++h) {
    int s = selmap[(size_t)row * NH + h];
    if (s >= 0 && s < uq) {
      const float* cp = corr + (size_t)((b * NH + h) * uq + s) * 512;
      y0 += cp[t];
      y1 += cp[t + 256];
    }
  }
  red[t] = y0 + y1;
  __syncthreads();
  for (int s = 128; s; s >>= 1) { if (t < s) red[t] += red[t + s]; __syncthreads(); }
  const float mu = red[0] * (1.f / 512.f);
  __syncthreads();
  const float d0 = y0 - mu, d1 = y1 - mu;
  red[t] = d0 * d0 + d1 * d1;
  __syncthreads();
  for (int s = 128; s; s >>= 1) { if (t < s) red[t] += red[t + s]; __syncthreads(); }
  const float rs = rsqrtf(red[0] * (1.f / 512.f) + 1e-5f);
  __syncthreads();
  out[(size_t)row * 512 + t] = d0 * rs * gamma[t] + beta[t];
  out[(size_t)row * 512 + 256 + t] = d1 * rs * gamma[256 + t] + beta[256 + t];
}

extern "C" void kernel_launch(void* const* d_in, const int* in_sizes, int n_in,
                              void* d_out, int out_size, void* d_ws, size_t ws_size,
                              hipStream_t stream) {
  const float* inQ = (const float*)d_in[0];
  const float* inK = (const float*)d_in[1];
  const float* inV = (const float*)d_in[2];
  const float* wQ = (const float*)d_in[3];
  const float* wK = (const float*)d_in[4];
  const float* wV = (const float*)d_in[5];
  const float* wFC = (const float*)d_in[6];
  const float* gamma = (const float*)d_in[7];
  const float* beta = (const float*)d_in[8];
  const int* samp = (const int*)d_in[9];

  const int nsamp = in_sizes[9];   // 77824
  const int uk = nsamp / NL;       // 38
  const int uq = uk;
  const int nqg = (uq + QB - 1) / QB;

  if (out_size < NB * NL * NDM + NB * NH * uq) return;

  const size_t perH = 3 * 131072 + 2048 + (size_t)uq * KSPLIT * 64 + (size_t)uq * KSPLIT * 2;
  const size_t fixed = (size_t)32 * uq * 64 + 2048 + 2048 + (size_t)32 * uq * 512
                     + (size_t)32 * uq + 32768 + 131072 + 131072 + 256;
  int hcg = 0;
  for (int c = 32; c >= 1; c >>= 1) {
    if ((perH * (size_t)c + fixed + 256) * 4ull <= ws_size) { hcg = c; break; }
  }
  if (hcg == 0) return;

  float* ws = (float*)d_ws;
  float* Qc = ws;
  float* Kc = Qc + (size_t)hcg * 131072;
  float* Vc = Kc + (size_t)hcg * 131072;
  float* Mb = Vc + (size_t)hcg * 131072;
  float* pacc = Mb + (size_t)hcg * 2048;
  float* pml = pacc + (size_t)hcg * uq * KSPLIT * 64;
  float* vals = pml + (size_t)hcg * uq * KSPLIT * 2;
  float* Vm = vals + (size_t)32 * uq * 64;
  float* base = Vm + 2048;
  float* corr = base + 2048;
  int* idxo = (int*)(corr + (size_t)32 * uq * 512);
  short* selmap = (short*)(idxo + (size_t)32 * uq);
  unsigned short* WTv = (unsigned short*)(selmap + 65536);   // 262144 bf16
  float* vparts = (float*)(WTv + 262144);                    // 131072 f

  float* out = (float*)d_out;
  float* outIdx = out + (size_t)NB * NL * NDM;

  wconv<<<1024, 256, 0, stream>>>(wV, WTv);
  vmean_colmean<<<dim3(NB, 64), 256, 0, stream>>>(inV, vparts);
  vmean_gemm<<<dim3(NB, 2), 256, 0, stream>>>(vparts, wV, Vm);

  for (int gh0 = 0; gh0 < NB * NH; gh0 += hcg) {
    proj3<<<dim3(16, hcg, 2), 256, 0, stream>>>(inQ, inK, wQ, wK, gh0, Qc, Kc);
    projV_mfma<<<dim3(32, hcg), 256, 0, stream>>>(inV, WTv, gh0, Vc);
    if (uk == 38)
      sample_scores_t<38><<<hcg * NL / 4, 256, 0, stream>>>(Qc, Kc, samp, Mb);
    else
      sample_scores_gen<<<hcg * NL / 4, 256, 0, stream>>>(Qc, Kc, samp, Mb, uk);
    topk_kernel<<<hcg, 256, 0, stream>>>(Mb, idxo + (size_t)gh0 * uq,
                                         outIdx + (size_t)gh0 * uq, uq);
    attn_part<<<dim3(hcg, nqg, KSPLIT), 256, 0, stream>>>(Qc, Kc, Vc,
                                                          idxo + (size_t)gh0 * uq,
                                                          pacc, pml, uq);
    attn_merge<<<hcg * uq, 64, 0, stream>>>(pacc, pml, vals + (size_t)gh0 * uq * ND, uq);
  }

  selmap_init<<<NB * NL * NH / 2 / 256, 256, 0, stream>>>(selmap);
  selmap_fill<<<(NB * NH * uq + 255) / 256, 256, 0, stream>>>(idxo, selmap, uq);
  base_gemm<<<dim3(NB, 2), 256, 0, stream>>>(Vm, wFC, base);
  corr_gemm<<<NB * NH * uq, 256, 0, stream>>>(vals, Vm, wFC, corr, uq);
  ln_fused<<<NB * NL, 256, 0, stream>>>(base, inQ, corr, selmap, gamma, beta, out, uq);
}